// Round 6
// baseline (684.357 us; speedup 1.0000x reference)
//
#include <hip/hip_runtime.h>
#include <math.h>

// Problem: B=64, S=2048, H=1024. Single-query attention + concat.
// out[b, 0:H]  = h_n[b]
// out[b, H:2H] = softmax_s(h_n[b]·enc[b,s,:]) @ enc[b,:,:]
//
// Timed window = 2.1GB ws poison-fill (~335us, fixed) + partial (~300us =
// 537MB @ ~1.8 TB/s) + final (~6us). Dead theories: addr phase (r1/r3),
// reg double-buffer (r4 null -- but compiler likely sank loads anyway),
// linear streams + residency (r5 worse).
//
// v6: DMA-decouple the read stream from the serial softmax chain.
// Each wave streams 64 rows through a private 4-slot LDS ring using
// global_load_lds_dwordx4 (fire-and-forget, no VGPR return) and COUNTED
// s_waitcnt vmcnt(12) -- never 0 in the main loop -- so 3-4 rows
// (12-16KB/wave, ~112KB/CU) stay in flight even while the wave sits in
// the ~500cy butterfly/exp/rescale chain. This is the one structural
// difference left between our kernel and the 6.4 TB/s fill: the fill's
// write queue never drains; our read queue did (compiler emits vmcnt(0)
// at first use -- guide rule #18). Inline-asm waitcnt + sched_barrier(0)
// force the schedule.

#define BB 64
#define SS 2048
#define HH 1024
#define NCHUNK 8               // S-chunks per batch -> 64*8 = 512 blocks (2/CU)
#define SCHUNK (SS / NCHUNK)   // 256 rows per block
#define NWAVE 4                // 256 threads
#define RUN (SCHUNK / NWAVE)   // 64 rows per wave
#define DEPTH 4                // LDS ring slots per wave (4KB each)

typedef float fvec4 __attribute__((ext_vector_type(4)));

// ws layout:
//   [0 .. B*NCHUNK*H)              : partial ctx accumulators (2 MB)
//   [B*NCHUNK*H .. +B*NCHUNK*2)    : (m, l) pairs per partial
#define WS_ML_OFF ((size_t)BB * NCHUNK * HH)

#define WAITVM(n) do { asm volatile("s_waitcnt vmcnt(" #n ")" ::: "memory"); \
                       __builtin_amdgcn_sched_barrier(0); } while (0)

// stage row (abs row index rowi, this wave's ring slot) : 4x global_load_lds_dwordx4
#define STAGE(rowi, slot) do {                                               \
    const float* g_ = gbase + (size_t)(rowi) * HH + lane * 4;                \
    float* l_ = lbase + (slot) * HH;                                         \
    _Pragma("unroll")                                                        \
    for (int j_ = 0; j_ < 4; ++j_)                                           \
        __builtin_amdgcn_global_load_lds(                                    \
            (const __attribute__((address_space(1))) void*)(g_ + j_ * 256),  \
            (__attribute__((address_space(3))) void*)(l_ + j_ * 256),        \
            16, 0, 0);                                                       \
} while (0)

// consume one staged row from ring slot: ds_read e, dot, butterfly, lazy softmax
#define CONSUME(slot) do {                                                   \
    const fvec4* eb_ = (const fvec4*)(lbase + (slot) * HH);                  \
    fvec4 e_[4];                                                             \
    _Pragma("unroll")                                                        \
    for (int j_ = 0; j_ < 4; ++j_) e_[j_] = eb_[j_ * 64 + lane];             \
    float d_ = 0.0f;                                                         \
    _Pragma("unroll")                                                        \
    for (int j_ = 0; j_ < 4; ++j_) {                                         \
        d_ += e_[j_].x * h4[j_].x + e_[j_].y * h4[j_].y                      \
            + e_[j_].z * h4[j_].z + e_[j_].w * h4[j_].w;                     \
    }                                                                        \
    _Pragma("unroll")                                                        \
    for (int off_ = 32; off_ > 0; off_ >>= 1)                                \
        d_ += __shfl_xor(d_, off_, 64);                                      \
    if (d_ <= m) {               /* common: max unchanged, no rescale */     \
        const float p_ = __expf(d_ - m);                                     \
        l += p_;                                                             \
        _Pragma("unroll")                                                    \
        for (int j_ = 0; j_ < 4; ++j_) {                                     \
            acc[j_].x = fmaf(p_, e_[j_].x, acc[j_].x);                       \
            acc[j_].y = fmaf(p_, e_[j_].y, acc[j_].y);                       \
            acc[j_].z = fmaf(p_, e_[j_].z, acc[j_].z);                       \
            acc[j_].w = fmaf(p_, e_[j_].w, acc[j_].w);                       \
        }                                                                    \
    } else {                     /* max grew: rescale, p = 1 */              \
        const float sc_ = __expf(m - d_);   /* first iter: exp(-inf)=0 */    \
        l = fmaf(l, sc_, 1.0f);                                              \
        m = d_;                                                              \
        _Pragma("unroll")                                                    \
        for (int j_ = 0; j_ < 4; ++j_) {                                     \
            acc[j_].x = fmaf(acc[j_].x, sc_, e_[j_].x);                      \
            acc[j_].y = fmaf(acc[j_].y, sc_, e_[j_].y);                      \
            acc[j_].z = fmaf(acc[j_].z, sc_, e_[j_].z);                      \
            acc[j_].w = fmaf(acc[j_].w, sc_, e_[j_].w);                      \
        }                                                                    \
    }                                                                        \
} while (0)

__global__ __launch_bounds__(256) void attn_partial_kernel(
    const float* __restrict__ enc, const float* __restrict__ hn,
    float* __restrict__ ws)
{
    // staging ring: [wave][slot][1024 floats] = 64 KB; the combine buffer
    // is aliased into this region after the streaming loop (dead by then).
    __shared__ float smem[NWAVE * DEPTH * HH];
    __shared__ float s_m[NWAVE];
    __shared__ float s_l[NWAVE];

    const int blk   = blockIdx.x;          // b * NCHUNK + chunk
    const int b     = blk >> 3;            // / NCHUNK
    const int chunk = blk & (NCHUNK - 1);
    const int tid   = threadIdx.x;
    const int wave  = tid >> 6;
    const int lane  = tid & 63;

    // Preload this lane's 16 h_n elements
    const fvec4* hn4 = (const fvec4*)(hn + (size_t)b * HH);
    fvec4 h4[4];
#pragma unroll
    for (int j = 0; j < 4; ++j) h4[j] = hn4[j * 64 + lane];

    const float* gbase = enc + (size_t)b * SS * HH
                       + (size_t)(chunk * SCHUNK + wave * RUN) * HH;
    float* lbase = smem + wave * DEPTH * HH;

    float m = -INFINITY;
    float l = 0.0f;
    fvec4 acc[4];
#pragma unroll
    for (int j = 0; j < 4; ++j) acc[j] = (fvec4)(0.f, 0.f, 0.f, 0.f);

    // prologue: fill the ring (rows 0..3 -> slots 0..3), 16 loads in flight
    STAGE(0, 0); STAGE(1, 1); STAGE(2, 2); STAGE(3, 3);

    // main loop: wait to 12 outstanding (row i landed), consume, restage.
    // vmcnt never drains to 0 -> 3-4 rows continuously in flight.
    for (int i = 0; i < RUN - DEPTH; ++i) {          // i = 0..59
        WAITVM(12);
        CONSUME(i & 3);
        STAGE(i + DEPTH, i & 3);
    }
    // tail: ring drains 12 -> 0
    WAITVM(12); CONSUME((RUN - 4) & 3);
    WAITVM(8);  CONSUME((RUN - 3) & 3);
    WAITVM(4);  CONSUME((RUN - 2) & 3);
    WAITVM(0);  CONSUME((RUN - 1) & 3);

    // ---- combine 4 wave-partials via LDS (alias staging region) ----
    __syncthreads();                       // all staging traffic dead
    float (*s_acc)[HH] = (float (*)[HH])smem;
#pragma unroll
    for (int j = 0; j < 4; ++j)
        ((fvec4*)s_acc[wave])[j * 64 + lane] = acc[j];
    if (lane == 0) { s_m[wave] = m; s_l[wave] = l; }
    __syncthreads();

    float M = fmaxf(fmaxf(s_m[0], s_m[1]), fmaxf(s_m[2], s_m[3]));
    float sc2[NWAVE];
    float L = 0.0f;
#pragma unroll
    for (int w = 0; w < NWAVE; ++w) {
        sc2[w] = __expf(s_m[w] - M);
        L += s_l[w] * sc2[w];
    }

    fvec4 ctx = (fvec4)(0.f, 0.f, 0.f, 0.f);
#pragma unroll
    for (int w = 0; w < NWAVE; ++w) {
        fvec4 a = ((const fvec4*)s_acc[w])[tid];
        ctx.x += sc2[w] * a.x;  ctx.y += sc2[w] * a.y;
        ctx.z += sc2[w] * a.z;  ctx.w += sc2[w] * a.w;
    }
    ((fvec4*)(ws + (size_t)blk * HH))[tid] = ctx;
    if (tid == 0) {
        ws[WS_ML_OFF + (size_t)blk * 2 + 0] = M;
        ws[WS_ML_OFF + (size_t)blk * 2 + 1] = L;
    }
}

__global__ __launch_bounds__(256) void attn_final_kernel(
    const float* __restrict__ hn, const float* __restrict__ ws,
    float* __restrict__ out)
{
    const int b   = blockIdx.x;
    const int tid = threadIdx.x;
    const float* ml = ws + WS_ML_OFF + (size_t)b * NCHUNK * 2;

    float M = -INFINITY;
#pragma unroll
    for (int c = 0; c < NCHUNK; ++c) M = fmaxf(M, ml[c * 2]);

    float sc[NCHUNK];
    float T = 0.0f;
#pragma unroll
    for (int c = 0; c < NCHUNK; ++c) {
        sc[c] = __expf(ml[c * 2] - M);
        T += sc[c] * ml[c * 2 + 1];
    }
    const float invT = 1.0f / T;

    fvec4 ctx = (fvec4)(0.f, 0.f, 0.f, 0.f);
#pragma unroll
    for (int c = 0; c < NCHUNK; ++c) {
        fvec4 a = ((const fvec4*)(ws + (size_t)(b * NCHUNK + c) * HH))[tid];
        ctx.x += sc[c] * a.x;  ctx.y += sc[c] * a.y;
        ctx.z += sc[c] * a.z;  ctx.w += sc[c] * a.w;
    }
    ctx.x *= invT; ctx.y *= invT; ctx.z *= invT; ctx.w *= invT;

    const fvec4 dec = ((const fvec4*)(hn + (size_t)b * HH))[tid];
    fvec4* o = (fvec4*)(out + (size_t)b * 2 * HH);
    o[tid]            = dec;   // dec_output half
    o[tid + (HH / 4)] = ctx;   // context half
}

extern "C" void kernel_launch(void* const* d_in, const int* in_sizes, int n_in,
                              void* d_out, int out_size, void* d_ws, size_t ws_size,
                              hipStream_t stream) {
    const float* enc = (const float*)d_in[0];   // (B, S, H) fp32
    const float* hn  = (const float*)d_in[1];   // (B, H) fp32
    float* out = (float*)d_out;                 // (B, 1, 2H) fp32
    float* ws  = (float*)d_ws;

    attn_partial_kernel<<<dim3(BB * NCHUNK), dim3(256), 0, stream>>>(enc, hn, ws);
    attn_final_kernel<<<dim3(BB), dim3(256), 0, stream>>>(hn, ws, out);
}